// Round 1
// baseline (1111.644 us; speedup 1.0000x reference)
//
#include <hip/hip_runtime.h>
#include <cstdint>
#include <cstddef>

using ushort = unsigned short;
using bf16x8 = __attribute__((ext_vector_type(8))) short;   // 8 bf16 (4 VGPRs)
using f32x4  = __attribute__((ext_vector_type(4))) float;   // MFMA acc

// ---- problem constants ----
#define S_    2048
#define HID_  4096
#define QL_   1536
#define KVL_  512
#define ROPE_ 64
#define NH_   32
constexpr float SCALE_ = 0.07216878364870322f;  // 1/sqrt(192)
constexpr float EPS_   = 1e-6f;

__device__ __forceinline__ float bf2f(ushort u){
  union { uint32_t i; float f; } v; v.i = ((uint32_t)u) << 16; return v.f;
}
__device__ __forceinline__ ushort f2bf(float f){
  union { uint32_t i; float f; } v; v.f = f;
  uint32_t r = v.i + 0x7FFFu + ((v.i >> 16) & 1u);   // RNE
  return (ushort)(r >> 16);
}
__device__ __forceinline__ void gload_lds16(const void* g, void* l){
  __builtin_amdgcn_global_load_lds((const __attribute__((address_space(1))) void*)g,
                                   (__attribute__((address_space(3))) void*)l, 16, 0, 0);
}

// ---------------- fp32 -> bf16 convert (vectorized) ----------------
__global__ __launch_bounds__(256) void convert_bf16(const float* __restrict__ in,
                                                    ushort* __restrict__ out, size_t n4){
  size_t i = (size_t)blockIdx.x * 256 + threadIdx.x;
  if (i < n4){
    float4 v = ((const float4*)in)[i];
    ushort4 o; o.x = f2bf(v.x); o.y = f2bf(v.y); o.z = f2bf(v.z); o.w = f2bf(v.w);
    ((ushort4*)out)[i] = o;
  }
}

// ---------------- tiled transpose + convert: out[n][k] = bf16(in[k][n]) ----------------
__global__ __launch_bounds__(256) void transpose_cvt(const float* __restrict__ in,
                                                     ushort* __restrict__ out,
                                                     int K, int N, int ldo){
  __shared__ float t[32][33];
  int k0 = blockIdx.x * 32, n0 = blockIdx.y * 32;
  int tx = threadIdx.x & 31, ty = threadIdx.x >> 5;
  #pragma unroll
  for (int i = ty; i < 32; i += 8){
    int k = k0 + i, n = n0 + tx;
    t[i][tx] = (k < K && n < N) ? in[(size_t)k * N + n] : 0.f;
  }
  __syncthreads();
  #pragma unroll
  for (int i = ty; i < 32; i += 8){
    int n = n0 + i, k = k0 + tx;
    if (n < N && k < K) out[(size_t)n * ldo + k] = f2bf(t[tx][i]);
  }
}

// ---------------- 128x128 bt-GEMM: C[M,N] = A[M,K] * B[N,K]^T  (m97 structure) ----------------
template<typename OutT>
__global__ __launch_bounds__(256, 2)
void gemm_bt(const ushort* __restrict__ A, const ushort* __restrict__ B,
             OutT* __restrict__ C, int M, int N, int K,
             int lda, int ldb, int ldc){
  __shared__ ushort As[128 * 32];
  __shared__ ushort Bs[128 * 32];
  int tid = threadIdx.x, wave = tid >> 6, lane = tid & 63;
  int m0 = blockIdx.x * 128, n0 = blockIdx.y * 128;
  int wr = wave >> 1, wc = wave & 1;          // 2x2 waves, 64x64 each
  f32x4 acc[4][4];
  #pragma unroll
  for (int i = 0; i < 4; i++) for (int j = 0; j < 4; j++) for (int q = 0; q < 4; q++) acc[i][j][q] = 0.f;

  int srow = tid >> 2, skq = (tid & 3) * 8;   // staging: thread -> 16B chunk
  const ushort* gA0 = A + (size_t)(m0 + srow) * lda + skq;
  const ushort* gA1 = A + (size_t)(m0 + 64 + srow) * lda + skq;
  const ushort* gB0 = B + (size_t)(n0 + srow) * ldb + skq;
  const ushort* gB1 = B + (size_t)(n0 + 64 + srow) * ldb + skq;
  char* lA = (char*)As + wave * 1024;         // wave-uniform LDS base (+lane*16 by HW)
  char* lB = (char*)Bs + wave * 1024;
  int rr = lane & 15, kq = (lane >> 4) * 8;

  int nk = K / 32;
  for (int kt = 0; kt < nk; ++kt){
    __syncthreads();
    gload_lds16(gA0, lA); gload_lds16(gA1, lA + 4096);
    gload_lds16(gB0, lB); gload_lds16(gB1, lB + 4096);
    gA0 += 32; gA1 += 32; gB0 += 32; gB1 += 32;
    __syncthreads();
    bf16x8 af[4], bg[4];
    #pragma unroll
    for (int i = 0; i < 4; i++) af[i] = *(const bf16x8*)&As[(wr * 64 + i * 16 + rr) * 32 + kq];
    #pragma unroll
    for (int j = 0; j < 4; j++) bg[j] = *(const bf16x8*)&Bs[(wc * 64 + j * 16 + rr) * 32 + kq];
    #pragma unroll
    for (int i = 0; i < 4; i++)
      #pragma unroll
      for (int j = 0; j < 4; j++)
        acc[i][j] = __builtin_amdgcn_mfma_f32_16x16x32_bf16(af[i], bg[j], acc[i][j], 0, 0, 0);
  }
  #pragma unroll
  for (int i = 0; i < 4; i++)
    #pragma unroll
    for (int j = 0; j < 4; j++){
      int r0 = m0 + wr * 64 + i * 16 + (lane >> 4) * 4;
      int c0 = n0 + wc * 64 + j * 16 + rr;
      if (c0 < N){
        #pragma unroll
        for (int q = 0; q < 4; q++){
          float v = acc[i][j][q];
          if constexpr (sizeof(OutT) == 2) C[(size_t)(r0 + q) * ldc + c0] = (OutT)f2bf(v);
          else                             C[(size_t)(r0 + q) * ldc + c0] = (OutT)v;
        }
      }
    }
}

// ---------------- fused rmsnorm(q_a), rmsnorm(kv_a), rope(k_pe) ----------------
__global__ __launch_bounds__(256) void norm_rope(const float* __restrict__ qkv,
                                                 const float* __restrict__ gqa,
                                                 const float* __restrict__ gkva,
                                                 ushort* __restrict__ qa_n,
                                                 ushort* __restrict__ kvlat,
                                                 ushort* __restrict__ kpe){
  int s = blockIdx.x, tid = threadIdx.x;
  const float* row = qkv + (size_t)s * 2112;
  __shared__ float red[4];
  __shared__ float bc[2];
  float ss = 0.f;
  for (int j = tid; j < 1536; j += 256){ float v = row[j]; ss += v * v; }
  #pragma unroll
  for (int m = 1; m < 64; m <<= 1) ss += __shfl_xor(ss, m);
  if ((tid & 63) == 0) red[tid >> 6] = ss;
  __syncthreads();
  if (tid == 0) bc[0] = rsqrtf((red[0] + red[1] + red[2] + red[3]) / 1536.f + EPS_);
  float s2 = 0.f;
  for (int j = tid; j < 512; j += 256){ float v = row[1536 + j]; s2 += v * v; }
  #pragma unroll
  for (int m = 1; m < 64; m <<= 1) s2 += __shfl_xor(s2, m);
  __syncthreads();
  if ((tid & 63) == 0) red[tid >> 6] = s2;
  __syncthreads();
  if (tid == 0) bc[1] = rsqrtf((red[0] + red[1] + red[2] + red[3]) / 512.f + EPS_);
  __syncthreads();
  float r1 = bc[0], r2 = bc[1];
  for (int j = tid; j < 1536; j += 256) qa_n[(size_t)s * 1536 + j] = f2bf(row[j] * r1 * gqa[j]);
  for (int j = tid; j < 512;  j += 256) kvlat[(size_t)s * 512 + j] = f2bf(row[1536 + j] * r2 * gkva[j]);
  if (tid < 32){
    int i = tid;
    float inv = powf(10000.f, -(float)i / 32.f);
    float an = (float)s * inv;
    float c = cosf(an), sn = sinf(an);
    float x1 = row[2048 + 2 * i], x2 = row[2048 + 2 * i + 1];
    kpe[(size_t)s * 64 + 2 * i]     = f2bf(x1 * c - x2 * sn);
    kpe[(size_t)s * 64 + 2 * i + 1] = f2bf(x2 * c + x1 * sn);
  }
}

// ---------------- in-place rope on q_pe slices of q (S x 6144 bf16) ----------------
__global__ __launch_bounds__(256) void rope_q(ushort* __restrict__ q){
  int s = blockIdx.x, tid = threadIdx.x;
  int i = tid & 31;
  float inv = powf(10000.f, -(float)i / 32.f);
  float an = (float)s * inv;
  float c = cosf(an), sn = sinf(an);
  for (int h = tid >> 5; h < 32; h += 8){
    size_t b = (size_t)s * 6144 + h * 192 + 128 + 2 * i;
    float x1 = bf2f(q[b]), x2 = bf2f(q[b + 1]);
    q[b]     = f2bf(x1 * c - x2 * sn);
    q[b + 1] = f2bf(x2 * c + x1 * sn);
  }
}

// ---------------- flash attention: per (q-tile 64, head). d=192 (128 nope + 64 rope), v=128 ----------------
__global__ __launch_bounds__(256, 2)
void flash_attn(const ushort* __restrict__ q, const ushort* __restrict__ ckv,
                const ushort* __restrict__ kpe, ushort* __restrict__ obuf){
  int qt = blockIdx.x, h = blockIdx.y;
  int tid = threadIdx.x, wave = tid >> 6, lane = tid & 63;
  int rr = lane & 15, kq = (lane >> 4) * 8;
  __shared__ ushort Qs[64][200];   // 192 used, pad -> 400B rows (2-way bank alias = free)
  __shared__ ushort Ks[64][200];
  __shared__ ushort VTs[128][72];  // V transposed: [v][t], 64 used
  __shared__ ushort Ps[64][72];
  int s0 = qt * 64;

  for (int c = tid; c < 64 * 48; c += 256){
    int r = c / 48, j4 = (c % 48) * 4;
    *(short4*)&Qs[r][j4] = *(const short4*)&q[(size_t)(s0 + r) * 6144 + h * 192 + j4];
  }
  __syncthreads();
  bf16x8 qf[6];
  #pragma unroll
  for (int ks = 0; ks < 6; ks++) qf[ks] = *(const bf16x8*)&Qs[wave * 16 + rr][ks * 32 + kq];

  float m[4], l[4]; f32x4 oacc[8];
  #pragma unroll
  for (int i = 0; i < 4; i++){ m[i] = -3e38f; l[i] = 0.f; }
  #pragma unroll
  for (int v = 0; v < 8; v++) for (int i = 0; i < 4; i++) oacc[v][i] = 0.f;

  for (int kt = 0; kt <= qt; ++kt){
    int t0 = kt * 64;
    __syncthreads();                       // prev-iter LDS reads done
    for (int c = tid; c < 64 * 48; c += 256){
      int t = c / 48, j4 = (c % 48) * 4;
      short4 val;
      if (j4 < 128) val = *(const short4*)&ckv[(size_t)(t0 + t) * 8192 + h * 256 + j4];
      else          val = *(const short4*)&kpe[(size_t)(t0 + t) * 64 + (j4 - 128)];
      *(short4*)&Ks[t][j4] = val;
    }
    for (int c = tid; c < 64 * 32; c += 256){
      int t = c / 32, v4 = (c % 32) * 4;
      short4 x = *(const short4*)&ckv[(size_t)(t0 + t) * 8192 + h * 256 + 128 + v4];
      VTs[v4][t] = x.x; VTs[v4 + 1][t] = x.y; VTs[v4 + 2][t] = x.z; VTs[v4 + 3][t] = x.w;
    }
    __syncthreads();

    f32x4 sc[4];
    #pragma unroll
    for (int nt = 0; nt < 4; nt++) for (int i2 = 0; i2 < 4; i2++) sc[nt][i2] = 0.f;
    #pragma unroll
    for (int ks = 0; ks < 6; ks++){
      #pragma unroll
      for (int nt = 0; nt < 4; nt++){
        bf16x8 kf = *(const bf16x8*)&Ks[nt * 16 + rr][ks * 32 + kq];
        sc[nt] = __builtin_amdgcn_mfma_f32_16x16x32_bf16(qf[ks], kf, sc[nt], 0, 0, 0);
      }
    }
    float sv[4][4], mt[4];
    #pragma unroll
    for (int i2 = 0; i2 < 4; i2++) mt[i2] = -3e38f;
    #pragma unroll
    for (int nt = 0; nt < 4; nt++)
      #pragma unroll
      for (int q2 = 0; q2 < 4; q2++){
        float v = sc[nt][q2] * SCALE_;
        if (kt == qt){
          int rowg = s0 + wave * 16 + (lane >> 4) * 4 + q2;
          int colg = t0 + nt * 16 + rr;
          if (colg > rowg) v = -3e38f;     // causal mask
        }
        sv[nt][q2] = v;
        mt[q2] = fmaxf(mt[q2], v);
      }
    #pragma unroll
    for (int msk = 1; msk < 16; msk <<= 1)
      #pragma unroll
      for (int q2 = 0; q2 < 4; q2++) mt[q2] = fmaxf(mt[q2], __shfl_xor(mt[q2], msk));
    float f[4], psum[4];
    #pragma unroll
    for (int q2 = 0; q2 < 4; q2++){
      float mn = fmaxf(m[q2], mt[q2]);
      f[q2] = __expf(m[q2] - mn);
      m[q2] = mn;
      psum[q2] = 0.f;
    }
    #pragma unroll
    for (int nt = 0; nt < 4; nt++)
      #pragma unroll
      for (int q2 = 0; q2 < 4; q2++){
        float p = __expf(sv[nt][q2] - m[q2]);
        psum[q2] += p;
        Ps[wave * 16 + (lane >> 4) * 4 + q2][nt * 16 + rr] = f2bf(p);
      }
    #pragma unroll
    for (int msk = 1; msk < 16; msk <<= 1)
      #pragma unroll
      for (int q2 = 0; q2 < 4; q2++) psum[q2] += __shfl_xor(psum[q2], msk);
    #pragma unroll
    for (int q2 = 0; q2 < 4; q2++) l[q2] = l[q2] * f[q2] + psum[q2];
    #pragma unroll
    for (int v = 0; v < 8; v++)
      #pragma unroll
      for (int q2 = 0; q2 < 4; q2++) oacc[v][q2] *= f[q2];
    #pragma unroll
    for (int ks = 0; ks < 2; ks++){
      bf16x8 pa = *(const bf16x8*)&Ps[wave * 16 + rr][ks * 32 + kq];
      #pragma unroll
      for (int vt = 0; vt < 8; vt++){
        bf16x8 vb = *(const bf16x8*)&VTs[vt * 16 + rr][ks * 32 + kq];
        oacc[vt] = __builtin_amdgcn_mfma_f32_16x16x32_bf16(pa, vb, oacc[vt], 0, 0, 0);
      }
    }
  }
  #pragma unroll
  for (int vt = 0; vt < 8; vt++)
    #pragma unroll
    for (int q2 = 0; q2 < 4; q2++){
      float v = oacc[vt][q2] / l[q2];
      obuf[(size_t)(s0 + wave * 16 + (lane >> 4) * 4 + q2) * 4096 + h * 128 + vt * 16 + rr] = f2bf(v);
    }
}

// ---------------- host ----------------
extern "C" void kernel_launch(void* const* d_in, const int* in_sizes, int n_in,
                              void* d_out, int out_size, void* d_ws, size_t ws_size,
                              hipStream_t stream){
  (void)in_sizes; (void)n_in; (void)out_size;
  const float* hidden = (const float*)d_in[0];
  const float* w_a    = (const float*)d_in[1];
  const float* g_qa   = (const float*)d_in[2];
  const float* w_qb   = (const float*)d_in[3];
  const float* g_kva  = (const float*)d_in[4];
  const float* w_kvb  = (const float*)d_in[5];
  const float* w_o    = (const float*)d_in[6];
  float* out = (float*)d_out;

  char* base = (char*)d_ws;
  size_t off = 0;
  auto take = [&](size_t b) -> char* { char* p = base + off; off += (b + 255) & ~(size_t)255; return p; };
  ushort* arenaW = (ushort*)take(33554432);                 // w_aT(2176 rows pad)/w_qbT/w_kvbT/w_oT, sequential reuse
  ushort* arenaB = (ushort*)take(33554432);                 // hidden bf16, then ckv
  char*   arenaC = take((size_t)S_ * 2112 * 4);             // qkv fp32, then obuf bf16
  ushort* qa_n   = (ushort*)take((size_t)S_ * QL_ * 2);
  ushort* qbuf   = (ushort*)take((size_t)S_ * 6144 * 2);
  ushort* kvlat  = (ushort*)take((size_t)S_ * KVL_ * 2);
  ushort* kpe    = (ushort*)take((size_t)S_ * ROPE_ * 2);
  if (off > ws_size) return;                                 // ws too small -> fail loudly (wrong output)

  ushort* hb   = arenaB;            // dead after GEMM1
  ushort* ckv  = arenaB;            // born GEMM3
  float*  qkv  = (float*)arenaC;    // dead after norm_rope
  ushort* obuf = (ushort*)arenaC;   // born flash

  convert_bf16 <<<8192, 256, 0, stream>>>(hidden, hb, (size_t)S_ * HID_ / 4);
  transpose_cvt<<<dim3(128, 66), 256, 0, stream>>>(w_a, arenaW, 4096, 2112, 4096);
  gemm_bt<float><<<dim3(16, 17), 256, 0, stream>>>(hb, arenaW, qkv, 2048, 2112, 4096, 4096, 4096, 2112);
  norm_rope    <<<2048, 256, 0, stream>>>(qkv, g_qa, g_kva, qa_n, kvlat, kpe);
  transpose_cvt<<<dim3(48, 192), 256, 0, stream>>>(w_qb, arenaW, 1536, 6144, 1536);
  gemm_bt<ushort><<<dim3(16, 48), 256, 0, stream>>>(qa_n, arenaW, qbuf, 2048, 6144, 1536, 1536, 1536, 6144);
  rope_q       <<<2048, 256, 0, stream>>>(qbuf);
  transpose_cvt<<<dim3(16, 256), 256, 0, stream>>>(w_kvb, arenaW, 512, 8192, 512);
  gemm_bt<ushort><<<dim3(16, 64), 256, 0, stream>>>(kvlat, arenaW, ckv, 2048, 8192, 512, 512, 512, 8192);
  flash_attn   <<<dim3(32, 32), 256, 0, stream>>>(qbuf, ckv, kpe, obuf);
  transpose_cvt<<<dim3(128, 128), 256, 0, stream>>>(w_o, arenaW, 4096, 4096, 4096);
  gemm_bt<float><<<dim3(16, 32), 256, 0, stream>>>(obuf, arenaW, out, 2048, 4096, 4096, 4096, 4096, 4096);
}

// Round 5
// 725.669 us; speedup vs baseline: 1.5319x; 1.5319x over previous
//
#include <hip/hip_runtime.h>
#include <cstdint>
#include <cstddef>

using ushort = unsigned short;
using bf16x8 = __attribute__((ext_vector_type(8))) short;   // 8 bf16 (4 VGPRs)
using f32x4  = __attribute__((ext_vector_type(4))) float;   // MFMA acc

// ---- problem constants ----
#define S_    2048
#define HID_  4096
#define QL_   1536
#define KVL_  512
#define ROPE_ 64
#define NH_   32
constexpr float SCALE_ = 0.07216878364870322f;  // 1/sqrt(192)
constexpr float EPS_   = 1e-6f;

__device__ __forceinline__ float bf2f(ushort u){
  union { uint32_t i; float f; } v; v.i = ((uint32_t)u) << 16; return v.f;
}
__device__ __forceinline__ ushort f2bf(float f){
  union { uint32_t i; float f; } v; v.f = f;
  uint32_t r = v.i + 0x7FFFu + ((v.i >> 16) & 1u);   // RNE
  return (ushort)(r >> 16);
}
__device__ __forceinline__ void gload_lds16(const void* g, void* l){
  __builtin_amdgcn_global_load_lds((const __attribute__((address_space(1))) void*)g,
                                   (__attribute__((address_space(3))) void*)l, 16, 0, 0);
}

// ---------------- fp32 -> bf16 convert (vectorized) ----------------
__global__ __launch_bounds__(256) void convert_bf16(const float* __restrict__ in,
                                                    ushort* __restrict__ out, size_t n4){
  size_t i = (size_t)blockIdx.x * 256 + threadIdx.x;
  if (i < n4){
    float4 v = ((const float4*)in)[i];
    ushort4 o; o.x = f2bf(v.x); o.y = f2bf(v.y); o.z = f2bf(v.z); o.w = f2bf(v.w);
    ((ushort4*)out)[i] = o;
  }
}

// ---------------- tiled transpose + convert: out[n][k] = bf16(in[k][n]) ----------------
__global__ __launch_bounds__(256) void transpose_cvt(const float* __restrict__ in,
                                                     ushort* __restrict__ out,
                                                     int K, int N, int ldo){
  __shared__ float t[32][33];
  int k0 = blockIdx.x * 32, n0 = blockIdx.y * 32;
  int tx = threadIdx.x & 31, ty = threadIdx.x >> 5;
  #pragma unroll
  for (int i = ty; i < 32; i += 8){
    int k = k0 + i, n = n0 + tx;
    t[i][tx] = (k < K && n < N) ? in[(size_t)k * N + n] : 0.f;
  }
  __syncthreads();
  #pragma unroll
  for (int i = ty; i < 32; i += 8){
    int n = n0 + i, k = k0 + tx;
    if (n < N && k < K) out[(size_t)n * ldo + k] = f2bf(t[tx][i]);
  }
}

// ---------------- 128x128 bt-GEMM: C[M,N] = A[M,K] * B[N,K]^T  (m97 structure) ----------------
// Optional vtout: for the kv_b GEMM (N=8192 = 32 heads x [128 K | 128 V]), also
// scatter the V half transposed to vtout[h*128+v][t] with short4 stores (free Vᵀ).
template<typename OutT>
__global__ __launch_bounds__(256, 2)
void gemm_bt(const ushort* __restrict__ A, const ushort* __restrict__ B,
             OutT* __restrict__ C, int M, int N, int K,
             int lda, int ldb, int ldc, ushort* __restrict__ vtout){
  __shared__ ushort As[128 * 32];
  __shared__ ushort Bs[128 * 32];
  int tid = threadIdx.x, wave = tid >> 6, lane = tid & 63;
  int m0 = blockIdx.x * 128, n0 = blockIdx.y * 128;
  int wr = wave >> 1, wc = wave & 1;          // 2x2 waves, 64x64 each
  f32x4 acc[4][4];
  #pragma unroll
  for (int i = 0; i < 4; i++) for (int j = 0; j < 4; j++) for (int q = 0; q < 4; q++) acc[i][j][q] = 0.f;

  int srow = tid >> 2, skq = (tid & 3) * 8;   // staging: thread -> 16B chunk
  const ushort* gA0 = A + (size_t)(m0 + srow) * lda + skq;
  const ushort* gA1 = A + (size_t)(m0 + 64 + srow) * lda + skq;
  const ushort* gB0 = B + (size_t)(n0 + srow) * ldb + skq;
  const ushort* gB1 = B + (size_t)(n0 + 64 + srow) * ldb + skq;
  char* lA = (char*)As + wave * 1024;         // wave-uniform LDS base (+lane*16 by HW)
  char* lB = (char*)Bs + wave * 1024;
  int rr = lane & 15, kq = (lane >> 4) * 8;

  int nk = K / 32;
  for (int kt = 0; kt < nk; ++kt){
    __syncthreads();
    gload_lds16(gA0, lA); gload_lds16(gA1, lA + 4096);
    gload_lds16(gB0, lB); gload_lds16(gB1, lB + 4096);
    gA0 += 32; gA1 += 32; gB0 += 32; gB1 += 32;
    __syncthreads();
    bf16x8 af[4], bg[4];
    #pragma unroll
    for (int i = 0; i < 4; i++) af[i] = *(const bf16x8*)&As[(wr * 64 + i * 16 + rr) * 32 + kq];
    #pragma unroll
    for (int j = 0; j < 4; j++) bg[j] = *(const bf16x8*)&Bs[(wc * 64 + j * 16 + rr) * 32 + kq];
    #pragma unroll
    for (int i = 0; i < 4; i++)
      #pragma unroll
      for (int j = 0; j < 4; j++)
        acc[i][j] = __builtin_amdgcn_mfma_f32_16x16x32_bf16(af[i], bg[j], acc[i][j], 0, 0, 0);
  }
  #pragma unroll
  for (int i = 0; i < 4; i++)
    #pragma unroll
    for (int j = 0; j < 4; j++){
      int r0 = m0 + wr * 64 + i * 16 + (lane >> 4) * 4;
      int c0 = n0 + wc * 64 + j * 16 + rr;
      if (c0 < N){
        #pragma unroll
        for (int q = 0; q < 4; q++){
          float v = acc[i][j][q];
          if constexpr (sizeof(OutT) == 2) C[(size_t)(r0 + q) * ldc + c0] = (OutT)f2bf(v);
          else                             C[(size_t)(r0 + q) * ldc + c0] = (OutT)v;
        }
        if (vtout){
          int hh = c0 >> 8, jj = c0 & 255;
          if (jj >= 128){
            short4 pk;
            pk.x = (short)f2bf(acc[i][j][0]); pk.y = (short)f2bf(acc[i][j][1]);
            pk.z = (short)f2bf(acc[i][j][2]); pk.w = (short)f2bf(acc[i][j][3]);
            *(short4*)&vtout[(size_t)(hh * 128 + (jj - 128)) * 2048 + r0] = pk;
          }
        }
      }
    }
}

// ---------------- fused rmsnorm(q_a), rmsnorm(kv_a), rope(k_pe) ----------------
__global__ __launch_bounds__(256) void norm_rope(const float* __restrict__ qkv,
                                                 const float* __restrict__ gqa,
                                                 const float* __restrict__ gkva,
                                                 ushort* __restrict__ qa_n,
                                                 ushort* __restrict__ kvlat,
                                                 ushort* __restrict__ kpe){
  int s = blockIdx.x, tid = threadIdx.x;
  const float* row = qkv + (size_t)s * 2112;
  __shared__ float red[4];
  __shared__ float bc[2];
  float ss = 0.f;
  for (int j = tid; j < 1536; j += 256){ float v = row[j]; ss += v * v; }
  #pragma unroll
  for (int m = 1; m < 64; m <<= 1) ss += __shfl_xor(ss, m);
  if ((tid & 63) == 0) red[tid >> 6] = ss;
  __syncthreads();
  if (tid == 0) bc[0] = rsqrtf((red[0] + red[1] + red[2] + red[3]) / 1536.f + EPS_);
  float s2 = 0.f;
  for (int j = tid; j < 512; j += 256){ float v = row[1536 + j]; s2 += v * v; }
  #pragma unroll
  for (int m = 1; m < 64; m <<= 1) s2 += __shfl_xor(s2, m);
  __syncthreads();
  if ((tid & 63) == 0) red[tid >> 6] = s2;
  __syncthreads();
  if (tid == 0) bc[1] = rsqrtf((red[0] + red[1] + red[2] + red[3]) / 512.f + EPS_);
  __syncthreads();
  float r1 = bc[0], r2 = bc[1];
  for (int j = tid; j < 1536; j += 256) qa_n[(size_t)s * 1536 + j] = f2bf(row[j] * r1 * gqa[j]);
  for (int j = tid; j < 512;  j += 256) kvlat[(size_t)s * 512 + j] = f2bf(row[1536 + j] * r2 * gkva[j]);
  if (tid < 32){
    int i = tid;
    float inv = powf(10000.f, -(float)i / 32.f);
    float an = (float)s * inv;
    float c = cosf(an), sn = sinf(an);
    float x1 = row[2048 + 2 * i], x2 = row[2048 + 2 * i + 1];
    kpe[(size_t)s * 64 + 2 * i]     = f2bf(x1 * c - x2 * sn);
    kpe[(size_t)s * 64 + 2 * i + 1] = f2bf(x2 * c + x1 * sn);
  }
}

// ---------------- in-place rope on q_pe slices of q (S x 6144 bf16) ----------------
__global__ __launch_bounds__(256) void rope_q(ushort* __restrict__ q){
  int s = blockIdx.x, tid = threadIdx.x;
  int i = tid & 31;
  float inv = powf(10000.f, -(float)i / 32.f);
  float an = (float)s * inv;
  float c = cosf(an), sn = sinf(an);
  for (int h = tid >> 5; h < 32; h += 8){
    size_t b = (size_t)s * 6144 + h * 192 + 128 + 2 * i;
    float x1 = bf2f(q[b]), x2 = bf2f(q[b + 1]);
    q[b]     = f2bf(x1 * c - x2 * sn);
    q[b + 1] = f2bf(x2 * c + x1 * sn);
  }
}

// ---------------- flash attention v2 (fixed K staging) ----------------
// Block = 4 waves x 16 q-rows = 64 q-rows, one head. Each block processes the
// PAIR of q-tiles {qt, 31-qt} -> exactly 33 K-tiles per block (causal balance).
// Q fragments straight from global (no Q LDS). V^T staged from the precomputed
// global vT[h*128+v][t] with row-contiguous 16B chunks (no scalar transpose).
// LDS = 25.6 + 18.4 + 9.2 = 53.2 KB -> 3 blocks/CU.
__global__ __launch_bounds__(256, 3)
void flash_attn(const ushort* __restrict__ q, const ushort* __restrict__ ckv,
                const ushort* __restrict__ kpe, const ushort* __restrict__ vT,
                ushort* __restrict__ obuf){
  __shared__ ushort Ks[64][200];   // 192 used; 400B rows (16B aligned)
  __shared__ ushort VTs[128][72];  // [v][t], 64 t used; 144B rows
  __shared__ ushort Ps[64][72];
  int h = blockIdx.y;
  int tid = threadIdx.x, wave = tid >> 6, lane = tid & 63;
  int rr = lane & 15, g = lane >> 4, kq = g * 8;
  const ushort* vTh = vT + (size_t)h * 128 * 2048;

  for (int half = 0; half < 2; ++half){
    int qt = half ? 31 - (int)blockIdx.x : (int)blockIdx.x;
    int s0 = qt * 64;
    bf16x8 qf[6];
    const ushort* qrow = q + (size_t)(s0 + wave * 16 + rr) * 6144 + h * 192;
    #pragma unroll
    for (int ks = 0; ks < 6; ks++) qf[ks] = *(const bf16x8*)(qrow + ks * 32 + kq);

    float m_[4], l_[4]; f32x4 oacc[8];
    #pragma unroll
    for (int i = 0; i < 4; i++){ m_[i] = -3e38f; l_[i] = 0.f; }
    #pragma unroll
    for (int v = 0; v < 8; v++) for (int i = 0; i < 4; i++) oacc[v][i] = 0.f;

    for (int kt = 0; kt <= qt; ++kt){
      int t0 = kt * 64;
      __syncthreads();                       // prior LDS reads done (incl. prev half)
      for (int c = tid; c < 1536; c += 256){ // K: 64 rows x 24 chunks of 8 ushorts (384B/row)
        int t = c / 24, ch = c % 24;
        bf16x8 val;
        if (ch < 16) val = *(const bf16x8*)&ckv[(size_t)(t0 + t) * 8192 + h * 256 + ch * 8];
        else         val = *(const bf16x8*)&kpe[(size_t)(t0 + t) * 64 + (ch - 16) * 8];
        *(bf16x8*)&Ks[t][ch * 8] = val;
      }
      for (int c = tid; c < 1024; c += 256){ // V^T: 128 rows x 8 16B-chunks of t
        int v = c >> 3, tc = c & 7;
        *(bf16x8*)&VTs[v][tc * 8] = *(const bf16x8*)&vTh[(size_t)v * 2048 + t0 + tc * 8];
      }
      __syncthreads();

      f32x4 sc[4];
      #pragma unroll
      for (int nt = 0; nt < 4; nt++) for (int i2 = 0; i2 < 4; i2++) sc[nt][i2] = 0.f;
      #pragma unroll
      for (int ks = 0; ks < 6; ks++){
        #pragma unroll
        for (int nt = 0; nt < 4; nt++){
          bf16x8 kf = *(const bf16x8*)&Ks[nt * 16 + rr][ks * 32 + kq];
          sc[nt] = __builtin_amdgcn_mfma_f32_16x16x32_bf16(qf[ks], kf, sc[nt], 0, 0, 0);
        }
      }
      float sv[4][4], mt[4];
      #pragma unroll
      for (int i2 = 0; i2 < 4; i2++) mt[i2] = -3e38f;
      #pragma unroll
      for (int nt = 0; nt < 4; nt++)
        #pragma unroll
        for (int q2 = 0; q2 < 4; q2++){
          float v = sc[nt][q2] * SCALE_;
          if (kt == qt){
            int rowg = s0 + wave * 16 + g * 4 + q2;
            int colg = t0 + nt * 16 + rr;
            if (colg > rowg) v = -3e38f;     // causal mask
          }
          sv[nt][q2] = v;
          mt[q2] = fmaxf(mt[q2], v);
        }
      #pragma unroll
      for (int msk = 1; msk < 16; msk <<= 1)
        #pragma unroll
        for (int q2 = 0; q2 < 4; q2++) mt[q2] = fmaxf(mt[q2], __shfl_xor(mt[q2], msk));
      float f[4], psum[4];
      #pragma unroll
      for (int q2 = 0; q2 < 4; q2++){
        float mn = fmaxf(m_[q2], mt[q2]);
        f[q2] = __expf(m_[q2] - mn);
        m_[q2] = mn;
        psum[q2] = 0.f;
      }
      #pragma unroll
      for (int nt = 0; nt < 4; nt++)
        #pragma unroll
        for (int q2 = 0; q2 < 4; q2++){
          float p = __expf(sv[nt][q2] - m_[q2]);
          psum[q2] += p;
          Ps[wave * 16 + g * 4 + q2][nt * 16 + rr] = f2bf(p);
        }
      #pragma unroll
      for (int msk = 1; msk < 16; msk <<= 1)
        #pragma unroll
        for (int q2 = 0; q2 < 4; q2++) psum[q2] += __shfl_xor(psum[q2], msk);
      #pragma unroll
      for (int q2 = 0; q2 < 4; q2++) l_[q2] = l_[q2] * f[q2] + psum[q2];
      #pragma unroll
      for (int v = 0; v < 8; v++)
        #pragma unroll
        for (int q2 = 0; q2 < 4; q2++) oacc[v][q2] *= f[q2];
      #pragma unroll
      for (int ks = 0; ks < 2; ks++){
        bf16x8 pa = *(const bf16x8*)&Ps[wave * 16 + rr][ks * 32 + kq];
        #pragma unroll
        for (int vt = 0; vt < 8; vt++){
          bf16x8 vb = *(const bf16x8*)&VTs[vt * 16 + rr][ks * 32 + kq];
          oacc[vt] = __builtin_amdgcn_mfma_f32_16x16x32_bf16(pa, vb, oacc[vt], 0, 0, 0);
        }
      }
    }
    #pragma unroll
    for (int vt = 0; vt < 8; vt++)
      #pragma unroll
      for (int q2 = 0; q2 < 4; q2++){
        float v = oacc[vt][q2] / l_[q2];
        obuf[(size_t)(s0 + wave * 16 + g * 4 + q2) * 4096 + h * 128 + vt * 16 + rr] = f2bf(v);
      }
  }
}

// ---------------- host ----------------
extern "C" void kernel_launch(void* const* d_in, const int* in_sizes, int n_in,
                              void* d_out, int out_size, void* d_ws, size_t ws_size,
                              hipStream_t stream){
  (void)in_sizes; (void)n_in; (void)out_size;
  const float* hidden = (const float*)d_in[0];
  const float* w_a    = (const float*)d_in[1];
  const float* g_qa   = (const float*)d_in[2];
  const float* w_qb   = (const float*)d_in[3];
  const float* g_kva  = (const float*)d_in[4];
  const float* w_kvb  = (const float*)d_in[5];
  const float* w_o    = (const float*)d_in[6];
  float* out = (float*)d_out;

  char* base = (char*)d_ws;
  size_t off = 0;
  auto take = [&](size_t b) -> char* { char* p = base + off; off += (b + 255) & ~(size_t)255; return p; };
  ushort* arenaW = (ushort*)take(33554432);                 // w_aT(2176 rows)/w_qbT/[w_kvbT | vT]/w_oT
  ushort* arenaB = (ushort*)take(33554432);                 // hidden bf16, then ckv
  char*   arenaC = take((size_t)S_ * 2112 * 4);             // qkv fp32, then obuf bf16
  ushort* qa_n   = (ushort*)take((size_t)S_ * QL_ * 2);
  ushort* qbuf   = (ushort*)take((size_t)S_ * 6144 * 2);
  ushort* kvlat  = (ushort*)take((size_t)S_ * KVL_ * 2);
  ushort* kpe    = (ushort*)take((size_t)S_ * ROPE_ * 2);
  if (off > ws_size) return;                                 // ws too small -> fail loudly

  ushort* hb   = arenaB;                    // dead after GEMM1
  ushort* ckv  = arenaB;                    // born GEMM3
  float*  qkv  = (float*)arenaC;            // dead after norm_rope
  ushort* obuf = (ushort*)arenaC;           // born flash
  ushort* vT   = arenaW + 8u * 1024 * 1024; // upper 16MB of arenaW (w_kvbT uses first 8MB;
                                            // w_oT overwrites only after flash is done)

  convert_bf16 <<<8192, 256, 0, stream>>>(hidden, hb, (size_t)S_ * HID_ / 4);
  transpose_cvt<<<dim3(128, 66), 256, 0, stream>>>(w_a, arenaW, 4096, 2112, 4096);
  gemm_bt<float><<<dim3(16, 17), 256, 0, stream>>>(hb, arenaW, qkv, 2048, 2112, 4096, 4096, 4096, 2112, nullptr);
  norm_rope    <<<2048, 256, 0, stream>>>(qkv, g_qa, g_kva, qa_n, kvlat, kpe);
  transpose_cvt<<<dim3(48, 192), 256, 0, stream>>>(w_qb, arenaW, 1536, 6144, 1536);
  gemm_bt<ushort><<<dim3(16, 48), 256, 0, stream>>>(qa_n, arenaW, qbuf, 2048, 6144, 1536, 1536, 1536, 6144, nullptr);
  rope_q       <<<2048, 256, 0, stream>>>(qbuf);
  transpose_cvt<<<dim3(16, 256), 256, 0, stream>>>(w_kvb, arenaW, 512, 8192, 512);
  gemm_bt<ushort><<<dim3(16, 64), 256, 0, stream>>>(kvlat, arenaW, ckv, 2048, 8192, 512, 512, 512, 8192, vT);
  flash_attn   <<<dim3(16, 32), 256, 0, stream>>>(qbuf, ckv, kpe, vT, obuf);
  transpose_cvt<<<dim3(128, 128), 256, 0, stream>>>(w_o, arenaW, 4096, 4096, 4096);
  gemm_bt<float><<<dim3(16, 32), 256, 0, stream>>>(obuf, arenaW, out, 2048, 4096, 4096, 4096, 4096, 4096, nullptr);
}